// Round 15
// baseline (692.418 us; speedup 1.0000x reference)
//
#include <hip/hip_runtime.h>
#include <math.h>

#define B_ 2
#define M_ 32768
#define N_ 4096
#define D_ 128
#define K_ 8

// ---------------------------------------------------------------------------
// Kernel 1: oracle f32 distance, round-15 hypothesis (einsum-optimize twin):
//   sp2 = (z*z + y*y) + x*x          c_einsum remainder: DESCENDING, no FMA
//   sg2 = (gz*gz + gy*gy) + gx*gx    c_einsum remainder: DESCENDING, no FMA
//   dot = fma(gz,pz, fma(gy,py, gx*px))  einsum(optimize=True)->BLAS asc-FMA
//   d2  = (sg2 + sp2) - 2*dot        literal (A+B)-2E, left-assoc
//   dist= sqrtf(fmaxf(d2,0))         correctly rounded
// Rank by f32 dist, strict < => lowest-index stable ties (lax.top_k).
// Block = 256 threads (4 waves); block owns 64 queries (lane l of each wave);
// wave w scans point quarter [w*1024,(w+1)*1024) from LDS. Sorted top-8 per
// lane in registers; 4 partials merged via LDS in ascending-index order.
// ---------------------------------------------------------------------------
__global__ __launch_bounds__(256) void knn_kernel(
    const float* __restrict__ grid_c, const float* __restrict__ pts,
    int* __restrict__ out_idx, float* __restrict__ out_w)
{
#pragma clang fp contract(off)
    __shared__ __align__(16) float sb[3 * N_];   // x|y|z planes; reused for merge
    __shared__ float sp2[N_];                    // |p|^2, DESCENDING plain

    const int tid   = threadIdx.x;
    const int qbase = blockIdx.x * 64;          // 32768 % 64 == 0 -> uniform b
    const int b     = qbase >> 15;
    const float* pb = pts + (size_t)b * N_ * 3;

    for (int i = tid; i < N_; i += 256) {
        const float x = pb[i * 3 + 0];
        const float y = pb[i * 3 + 1];
        const float z = pb[i * 3 + 2];
        sb[i]          = x;
        sb[N_ + i]     = y;
        sb[2 * N_ + i] = z;
        sp2[i] = (z * z + y * y) + x * x;       // DESCENDING, no fma
    }
    __syncthreads();

    const int lane = tid & 63;
    const int wv   = tid >> 6;
    const int q    = qbase + lane;
    const float gx = grid_c[q * 3 + 0];
    const float gy = grid_c[q * 3 + 1];
    const float gz = grid_c[q * 3 + 2];
    const float sg2 = (gz * gz + gy * gy) + gx * gx;   // DESCENDING, no fma

    float bd[8];
    int   bi[8];
#pragma unroll
    for (int u = 0; u < 8; ++u) { bd[u] = 3.4e38f; bi[u] = 0; }

    const int t0 = wv * (N_ / 4);
    const int t1 = t0 + (N_ / 4);
    for (int t = t0; t < t1; ++t) {
        const float px = sb[t];
        const float py = sb[N_ + t];
        const float pz = sb[2 * N_ + t];
        const float dot = fmaf(gz, pz, fmaf(gy, py, gx * px));  // asc-FMA chain
        const float d2  = (sg2 + sp2[t]) - 2.0f * dot;          // left-assoc
        const float dist = sqrtf(fmaxf(d2, 0.0f));
        if (dist < bd[7]) {                // strict <: lowest-index stable ties
            bd[7] = dist; bi[7] = t;
#pragma unroll
            for (int u = 6; u >= 0; --u) {
                if (bd[u + 1] < bd[u]) {
                    float tf = bd[u]; bd[u] = bd[u + 1]; bd[u + 1] = tf;
                    int   ti = bi[u]; bi[u] = bi[u + 1]; bi[u + 1] = ti;
                }
            }
        }
    }

    __syncthreads();   // all point reads done -> safe to reuse sb
    {
        float* md = sb;                       // [64][32] f32 (8 KB)
        int*   mi = (int*)(sb + 2048);        // [64][32] int (8 KB)
        const int base = lane * 32 + wv * 8;
#pragma unroll
        for (int u = 0; u < 8; ++u) { md[base + u] = bd[u]; mi[base + u] = bi[u]; }
    }
    __syncthreads();

    if (tid < 64) {
        const float* md = sb;
        const int*   mi = (const int*)(sb + 2048);
        float ed[8];
        int   ei[8];
#pragma unroll
        for (int u = 0; u < 8; ++u) { ed[u] = 3.4e38f; ei[u] = 0; }
        // s2 ascending = wave order = ascending index blocks -> stable merge
        for (int s2 = 0; s2 < 32; ++s2) {
            float v  = md[tid * 32 + s2];
            int   vi = mi[tid * 32 + s2];
            if (v < ed[7]) {
                ed[7] = v; ei[7] = vi;
#pragma unroll
                for (int u = 6; u >= 0; --u) {
                    if (ed[u + 1] < ed[u]) {
                        float tf = ed[u]; ed[u] = ed[u + 1]; ed[u + 1] = tf;
                        int   ti = ei[u]; ei[u] = ei[u + 1]; ei[u + 1] = ti;
                    }
                }
            }
        }
        // inverse-distance weights in f32 (continuous path)
        float wk8[8];
#pragma unroll
        for (int u = 0; u < 8; ++u)
            wk8[u] = 1.0f / (ed[u] + 1e-6f);
        float wsum = wk8[0];
#pragma unroll
        for (int u = 1; u < 8; ++u) wsum = wsum + wk8[u];
        const float winv = 1.0f / wsum;
        const int qq = qbase + tid;
#pragma unroll
        for (int u = 0; u < 8; ++u) {
            out_idx[qq * 8 + u] = ei[u];
            out_w[qq * 8 + u]   = wk8[u] * winv;
        }
    }
}

// ---------------------------------------------------------------------------
// Kernel 2: per-neighbor MLP + weighted reduce + LayerNorm. (unchanged —
// continuous path, rounding differences are ~1e-5 vs 4.2e-2 threshold)
// Block = 256 threads = 8 query-slots x 32 d-groups (4 consecutive d each).
// ---------------------------------------------------------------------------
__global__ __launch_bounds__(256) void gno_kernel(
    const float* __restrict__ grid_c, const float* __restrict__ pts,
    const float* __restrict__ feats,
    const float* __restrict__ W1, const float* __restrict__ b1,
    const float* __restrict__ W2, const float* __restrict__ b2,
    const float* __restrict__ gmm, const float* __restrict__ bta,
    const int* __restrict__ kidx, const float* __restrict__ kw,
    float* __restrict__ out)
{
    __shared__ float sh[8][8][D_];      // [q][k][j]  32 KB
    __shared__ float srel[8][8][4];
    __shared__ float swt[8][8];
    __shared__ int   sid[8][8];
    __shared__ float sW1[4 * D_];       // W1 (3*D) then b1 (D)

    const int tid = threadIdx.x;
    const int qb8 = blockIdx.x * 8;

    for (int i = tid; i < 4 * D_; i += 256)
        sW1[i] = (i < 3 * D_) ? W1[i] : b1[i - 3 * D_];

    if (tid < 64) {
        const int qq = tid >> 3, k = tid & 7;
        const int gq = qb8 + qq;
        const int id = kidx[gq * 8 + k];
        sid[qq][k] = id;
        swt[qq][k] = kw[gq * 8 + k];
        const int bb = gq >> 15;
        const float* pp = pts + ((size_t)bb * N_ + id) * 3;
        srel[qq][k][0] = grid_c[gq * 3 + 0] - pp[0];
        srel[qq][k][1] = grid_c[gq * 3 + 1] - pp[1];
        srel[qq][k][2] = grid_c[gq * 3 + 2] - pp[2];
    }
    __syncthreads();

    const int qs = tid >> 5;
    const int dg = tid & 31;

    // ---- Phase A: h into LDS --------------------------------------------
#pragma unroll
    for (int k = 0; k < 8; ++k) {
        const float rx = srel[qs][k][0];
        const float ry = srel[qs][k][1];
        const float rz = srel[qs][k][2];
        float hr[4];
#pragma unroll
        for (int jj = 0; jj < 4; ++jj) {
            const int j = dg * 4 + jj;
            float u = rx * sW1[j] + ry * sW1[D_ + j] + rz * sW1[2 * D_ + j]
                      + sW1[3 * D_ + j];
            hr[jj] = 0.5f * u * (1.0f + erff(u * 0.70710678118654752f));
        }
        *(float4*)&sh[qs][k][dg * 4] = *(float4*)hr;
    }
    __syncthreads();

    // ---- Phase B: kappa = h @ W2, combine -------------------------------
    float acc[8][4];
#pragma unroll
    for (int k = 0; k < 8; ++k)
#pragma unroll
        for (int c = 0; c < 4; ++c) acc[k][c] = 0.0f;

    const float* w2p = W2 + dg * 4;
#pragma unroll 2
    for (int j = 0; j < D_; ++j) {
        const float4 wv4 = *(const float4*)(w2p + (size_t)j * D_);
#pragma unroll
        for (int k = 0; k < 8; ++k) {
            const float h = sh[qs][k][j];
            acc[k][0] += h * wv4.x;
            acc[k][1] += h * wv4.y;
            acc[k][2] += h * wv4.z;
            acc[k][3] += h * wv4.w;
        }
    }

    const int gq = qb8 + qs;
    const int bb = gq >> 15;
    const float4 b2v = *(const float4*)(b2 + dg * 4);

    float o0 = 0.0f, o1 = 0.0f, o2 = 0.0f, o3 = 0.0f;
#pragma unroll
    for (int k = 0; k < 8; ++k) {
        const float4 f =
            *(const float4*)(feats + ((size_t)bb * N_ + sid[qs][k]) * D_ + dg * 4);
        const float wk = swt[qs][k];
        o0 += wk * f.x * (acc[k][0] + b2v.x);
        o1 += wk * f.y * (acc[k][1] + b2v.y);
        o2 += wk * f.z * (acc[k][2] + b2v.z);
        o3 += wk * f.w * (acc[k][3] + b2v.w);
    }

    // ---- LayerNorm over D=128 (32 lanes x 4 vals) -----------------------
    float s = o0 + o1 + o2 + o3;
#pragma unroll
    for (int off = 16; off > 0; off >>= 1) s += __shfl_xor(s, off, 32);
    const float mu = s * (1.0f / 128.0f);
    const float v0 = o0 - mu, v1 = o1 - mu, v2 = o2 - mu, v3 = o3 - mu;
    float vs = v0 * v0 + v1 * v1 + v2 * v2 + v3 * v3;
#pragma unroll
    for (int off = 16; off > 0; off >>= 1) vs += __shfl_xor(vs, off, 32);
    const float inv = 1.0f / sqrtf(vs * (1.0f / 128.0f) + 1e-5f);

    const float4 gv = *(const float4*)(gmm + dg * 4);
    const float4 bv = *(const float4*)(bta + dg * 4);
    float4 ov;
    ov.x = v0 * inv * gv.x + bv.x;
    ov.y = v1 * inv * gv.y + bv.y;
    ov.z = v2 * inv * gv.z + bv.z;
    ov.w = v3 * inv * gv.w + bv.w;
    *(float4*)(out + (size_t)gq * D_ + dg * 4) = ov;
}

// ---------------------------------------------------------------------------
extern "C" void kernel_launch(void* const* d_in, const int* in_sizes, int n_in,
                              void* d_out, int out_size, void* d_ws, size_t ws_size,
                              hipStream_t stream)
{
    (void)in_sizes; (void)n_in; (void)out_size; (void)ws_size;
    const float* grid_c = (const float*)d_in[0];
    const float* pts    = (const float*)d_in[1];
    const float* feats  = (const float*)d_in[2];
    const float* W1     = (const float*)d_in[3];
    const float* b1     = (const float*)d_in[4];
    const float* W2     = (const float*)d_in[5];
    const float* b2     = (const float*)d_in[6];
    const float* gmm    = (const float*)d_in[7];
    const float* bta    = (const float*)d_in[8];
    float* out = (float*)d_out;

    int*   kidx = (int*)d_ws;
    float* kw   = (float*)((char*)d_ws + (size_t)B_ * M_ * K_ * sizeof(int));

    knn_kernel<<<(B_ * M_) / 64, 256, 0, stream>>>(grid_c, pts, kidx, kw);
    gno_kernel<<<(B_ * M_) / 8, 256, 0, stream>>>(grid_c, pts, feats, W1, b1,
                                                  W2, b2, gmm, bta, kidx, kw, out);
}

// Round 16
// 682.598 us; speedup vs baseline: 1.0144x; 1.0144x over previous
//
#include <hip/hip_runtime.h>
#include <math.h>

#define B_ 2
#define M_ 32768
#define N_ 4096
#define D_ 128
#define K_ 8

// ---------------------------------------------------------------------------
// Prep: pack points as float4(x,y,z,|p|^2) with |p|^2 = (z*z+y*y)+x*x
// (descending plain — the verified oracle rounding), no contraction.
// ---------------------------------------------------------------------------
__global__ __launch_bounds__(256) void prep_kernel(
    const float* __restrict__ pts, float4* __restrict__ pts4)
{
#pragma clang fp contract(off)
    const int i = blockIdx.x * 256 + threadIdx.x;
    if (i < B_ * N_) {
        const float x = pts[i * 3 + 0];
        const float y = pts[i * 3 + 1];
        const float z = pts[i * 3 + 2];
        float4 v;
        v.x = x; v.y = y; v.z = z;
        v.w = (z * z + y * y) + x * x;          // DESCENDING, no fma
        pts4[i] = v;
    }
}

// ---------------------------------------------------------------------------
// knn: verified oracle semantics (FROZEN):
//   sg2 = (gz*gz+gy*gy)+gx*gx   descending plain
//   dot = fma(gz,pz, fma(gy,py, gx*px))  ascending FMA chain
//   d2  = fma(dot,-2, sg2+sp2)  == (sg2+sp2) - 2*dot bitwise (2*dot exact)
//   dist= sqrtf(fmaxf(d2,0)); rank by dist, strict < (lowest-index ties)
// Structure: block = 256 thr = 4 waves; block owns 128 queries; wave w =
// queries (w&1)*64+lane, scanning point HALF (w>>1) (2048 pts, ascending).
// Points read via wave-uniform float4 loads (scalar-cache/L1 broadcast; no
// LDS staging -> occupancy up). Halves merged in-block via padded LDS
// (half0 first = ascending-index stable merge, identical tie semantics).
// ---------------------------------------------------------------------------
__global__ __launch_bounds__(256) void knn_kernel(
    const float* __restrict__ grid_c, const float4* __restrict__ pts4,
    int* __restrict__ out_idx, float* __restrict__ out_w)
{
#pragma clang fp contract(off)
    __shared__ float sd[128][2][9];   // [q_local][half][8 + pad]
    __shared__ int   si[128][2][9];

    const int tid   = threadIdx.x;
    const int wv    = tid >> 6;
    const int lane  = tid & 63;
    const int qbase = blockIdx.x * 128;         // 32768 % 128 == 0 -> uniform b
    const int b     = qbase >> 15;
    const int qloc  = (wv & 1) * 64 + lane;
    const int half  = wv >> 1;
    const int q     = qbase + qloc;

    const float gx = grid_c[q * 3 + 0];
    const float gy = grid_c[q * 3 + 1];
    const float gz = grid_c[q * 3 + 2];
    const float sg2 = (gz * gz + gy * gy) + gx * gx;   // DESCENDING, no fma

    float bd[8];
    int   bi[8];
#pragma unroll
    for (int u = 0; u < 8; ++u) { bd[u] = 3.4e38f; bi[u] = 0; }

    const int toff = half * (N_ / 2);
    const float4* __restrict__ pb4 = pts4 + (size_t)b * N_ + toff;

    for (int t = 0; t < N_ / 2; ++t) {
        const float4 pp = pb4[t];               // wave-uniform -> s_load/L1
        const float dot = fmaf(gz, pp.z, fmaf(gy, pp.y, gx * pp.x));
        const float d2  = fmaf(dot, -2.0f, sg2 + pp.w);   // == (A+B)-2*dot
        const float dist = sqrtf(fmaxf(d2, 0.0f));
        if (dist < bd[7]) {                     // strict <: stable ties
            bd[7] = dist; bi[7] = toff + t;
#pragma unroll
            for (int u = 6; u >= 0; --u) {
                if (bd[u + 1] < bd[u]) {
                    float tf = bd[u]; bd[u] = bd[u + 1]; bd[u + 1] = tf;
                    int   ti = bi[u]; bi[u] = bi[u + 1]; bi[u + 1] = ti;
                }
            }
        }
    }

#pragma unroll
    for (int u = 0; u < 8; ++u) { sd[qloc][half][u] = bd[u]; si[qloc][half][u] = bi[u]; }
    __syncthreads();

    if (tid < 128) {
        float ed[8];
        int   ei[8];
#pragma unroll
        for (int u = 0; u < 8; ++u) { ed[u] = 3.4e38f; ei[u] = 0; }
        // half 0 (lower indices) first -> stable lowest-index tie-break
        for (int h = 0; h < 2; ++h) {
#pragma unroll
            for (int u2 = 0; u2 < 8; ++u2) {
                float v  = sd[tid][h][u2];
                int   vi = si[tid][h][u2];
                if (v < ed[7]) {
                    ed[7] = v; ei[7] = vi;
#pragma unroll
                    for (int u = 6; u >= 0; --u) {
                        if (ed[u + 1] < ed[u]) {
                            float tf = ed[u]; ed[u] = ed[u + 1]; ed[u + 1] = tf;
                            int   ti = ei[u]; ei[u] = ei[u + 1]; ei[u + 1] = ti;
                        }
                    }
                }
            }
        }
        // inverse-distance weights (verified rounding: f32, sequential sum)
        float wk8[8];
#pragma unroll
        for (int u = 0; u < 8; ++u)
            wk8[u] = 1.0f / (ed[u] + 1e-6f);
        float wsum = wk8[0];
#pragma unroll
        for (int u = 1; u < 8; ++u) wsum = wsum + wk8[u];
        const float winv = 1.0f / wsum;
        const int qq = qbase + tid;
#pragma unroll
        for (int u = 0; u < 8; ++u) {
            out_idx[qq * 8 + u] = ei[u];
            out_w[qq * 8 + u]   = wk8[u] * winv;
        }
    }
}

// ---------------------------------------------------------------------------
// gno: per-neighbor MLP + weighted reduce + LayerNorm (continuous path).
// Phase B now uses float4 LDS reads (ds_read_b128): 8 LDS ops per 128 FMAs.
// W1 rows held in registers (no LDS staging). j-accumulation order unchanged.
// ---------------------------------------------------------------------------
__global__ __launch_bounds__(256) void gno_kernel(
    const float* __restrict__ grid_c, const float* __restrict__ pts,
    const float* __restrict__ feats,
    const float* __restrict__ W1, const float* __restrict__ b1,
    const float* __restrict__ W2, const float* __restrict__ b2,
    const float* __restrict__ gmm, const float* __restrict__ bta,
    const int* __restrict__ kidx, const float* __restrict__ kw,
    float* __restrict__ out)
{
    __shared__ float sh[8][8][D_];      // [q][k][j]  32 KB
    __shared__ float srel[8][8][4];
    __shared__ float swt[8][8];
    __shared__ int   sid[8][8];

    const int tid = threadIdx.x;
    const int qb8 = blockIdx.x * 8;

    if (tid < 64) {
        const int qq = tid >> 3, k = tid & 7;
        const int gq = qb8 + qq;
        const int id = kidx[gq * 8 + k];
        sid[qq][k] = id;
        swt[qq][k] = kw[gq * 8 + k];
        const int bb = gq >> 15;
        const float* pp = pts + ((size_t)bb * N_ + id) * 3;
        srel[qq][k][0] = grid_c[gq * 3 + 0] - pp[0];
        srel[qq][k][1] = grid_c[gq * 3 + 1] - pp[1];
        srel[qq][k][2] = grid_c[gq * 3 + 2] - pp[2];
    }

    const int qs = tid >> 5;
    const int dg = tid & 31;

    const float4 w1r0 = *(const float4*)(W1 + dg * 4);
    const float4 w1r1 = *(const float4*)(W1 + D_ + dg * 4);
    const float4 w1r2 = *(const float4*)(W1 + 2 * D_ + dg * 4);
    const float4 w1bb = *(const float4*)(b1 + dg * 4);
    __syncthreads();

    // ---- Phase A: h into LDS --------------------------------------------
#pragma unroll
    for (int k = 0; k < 8; ++k) {
        const float rx = srel[qs][k][0];
        const float ry = srel[qs][k][1];
        const float rz = srel[qs][k][2];
        float hr[4];
        {
            float u0 = rx * w1r0.x + ry * w1r1.x + rz * w1r2.x + w1bb.x;
            float u1 = rx * w1r0.y + ry * w1r1.y + rz * w1r2.y + w1bb.y;
            float u2 = rx * w1r0.z + ry * w1r1.z + rz * w1r2.z + w1bb.z;
            float u3 = rx * w1r0.w + ry * w1r1.w + rz * w1r2.w + w1bb.w;
            hr[0] = 0.5f * u0 * (1.0f + erff(u0 * 0.70710678118654752f));
            hr[1] = 0.5f * u1 * (1.0f + erff(u1 * 0.70710678118654752f));
            hr[2] = 0.5f * u2 * (1.0f + erff(u2 * 0.70710678118654752f));
            hr[3] = 0.5f * u3 * (1.0f + erff(u3 * 0.70710678118654752f));
        }
        *(float4*)&sh[qs][k][dg * 4] = *(float4*)hr;
    }
    __syncthreads();

    // ---- Phase B: kappa = h @ W2, combine -------------------------------
    float acc[8][4];
#pragma unroll
    for (int k = 0; k < 8; ++k)
#pragma unroll
        for (int c = 0; c < 4; ++c) acc[k][c] = 0.0f;

    const float* w2p = W2 + dg * 4;
    for (int j0 = 0; j0 < D_; j0 += 4) {
        float4 hv[8];
#pragma unroll
        for (int k = 0; k < 8; ++k)
            hv[k] = *(const float4*)&sh[qs][k][j0];
        const float4 wa = *(const float4*)(w2p + (size_t)j0 * D_);
        const float4 wb = *(const float4*)(w2p + (size_t)(j0 + 1) * D_);
        const float4 wc = *(const float4*)(w2p + (size_t)(j0 + 2) * D_);
        const float4 wd = *(const float4*)(w2p + (size_t)(j0 + 3) * D_);
#pragma unroll
        for (int k = 0; k < 8; ++k) {
            acc[k][0] += hv[k].x * wa.x; acc[k][1] += hv[k].x * wa.y;
            acc[k][2] += hv[k].x * wa.z; acc[k][3] += hv[k].x * wa.w;
            acc[k][0] += hv[k].y * wb.x; acc[k][1] += hv[k].y * wb.y;
            acc[k][2] += hv[k].y * wb.z; acc[k][3] += hv[k].y * wb.w;
            acc[k][0] += hv[k].z * wc.x; acc[k][1] += hv[k].z * wc.y;
            acc[k][2] += hv[k].z * wc.z; acc[k][3] += hv[k].z * wc.w;
            acc[k][0] += hv[k].w * wd.x; acc[k][1] += hv[k].w * wd.y;
            acc[k][2] += hv[k].w * wd.z; acc[k][3] += hv[k].w * wd.w;
        }
    }

    const int gq = qb8 + qs;
    const int bb = gq >> 15;
    const float4 b2v = *(const float4*)(b2 + dg * 4);

    float o0 = 0.0f, o1 = 0.0f, o2 = 0.0f, o3 = 0.0f;
#pragma unroll
    for (int k = 0; k < 8; ++k) {
        const float4 f =
            *(const float4*)(feats + ((size_t)bb * N_ + sid[qs][k]) * D_ + dg * 4);
        const float wk = swt[qs][k];
        o0 += wk * f.x * (acc[k][0] + b2v.x);
        o1 += wk * f.y * (acc[k][1] + b2v.y);
        o2 += wk * f.z * (acc[k][2] + b2v.z);
        o3 += wk * f.w * (acc[k][3] + b2v.w);
    }

    // ---- LayerNorm over D=128 (32 lanes x 4 vals) -----------------------
    float s = o0 + o1 + o2 + o3;
#pragma unroll
    for (int off = 16; off > 0; off >>= 1) s += __shfl_xor(s, off, 32);
    const float mu = s * (1.0f / 128.0f);
    const float v0 = o0 - mu, v1 = o1 - mu, v2 = o2 - mu, v3 = o3 - mu;
    float vs = v0 * v0 + v1 * v1 + v2 * v2 + v3 * v3;
#pragma unroll
    for (int off = 16; off > 0; off >>= 1) vs += __shfl_xor(vs, off, 32);
    const float inv = 1.0f / sqrtf(vs * (1.0f / 128.0f) + 1e-5f);

    const float4 gv = *(const float4*)(gmm + dg * 4);
    const float4 bv = *(const float4*)(bta + dg * 4);
    float4 ov;
    ov.x = v0 * inv * gv.x + bv.x;
    ov.y = v1 * inv * gv.y + bv.y;
    ov.z = v2 * inv * gv.z + bv.z;
    ov.w = v3 * inv * gv.w + bv.w;
    *(float4*)(out + (size_t)gq * D_ + dg * 4) = ov;
}

// ---------------------------------------------------------------------------
extern "C" void kernel_launch(void* const* d_in, const int* in_sizes, int n_in,
                              void* d_out, int out_size, void* d_ws, size_t ws_size,
                              hipStream_t stream)
{
    (void)in_sizes; (void)n_in; (void)out_size; (void)ws_size;
    const float* grid_c = (const float*)d_in[0];
    const float* pts    = (const float*)d_in[1];
    const float* feats  = (const float*)d_in[2];
    const float* W1     = (const float*)d_in[3];
    const float* b1     = (const float*)d_in[4];
    const float* W2     = (const float*)d_in[5];
    const float* b2     = (const float*)d_in[6];
    const float* gmm    = (const float*)d_in[7];
    const float* bta    = (const float*)d_in[8];
    float* out = (float*)d_out;

    int*    kidx = (int*)d_ws;                                        // 2 MB
    float*  kw   = (float*)((char*)d_ws + (size_t)B_ * M_ * K_ * 4);  // 2 MB
    float4* pts4 = (float4*)((char*)d_ws + (size_t)B_ * M_ * K_ * 8); // 128 KB

    prep_kernel<<<(B_ * N_ + 255) / 256, 256, 0, stream>>>(pts, pts4);
    knn_kernel<<<(B_ * M_) / 128, 256, 0, stream>>>(grid_c, pts4, kidx, kw);
    gno_kernel<<<(B_ * M_) / 8, 256, 0, stream>>>(grid_c, pts, feats, W1, b1,
                                                  W2, b2, gmm, bta, kidx, kw, out);
}

// Round 17
// 567.331 us; speedup vs baseline: 1.2205x; 1.2032x over previous
//
#include <hip/hip_runtime.h>
#include <math.h>

#define B_ 2
#define M_ 32768
#define N_ 4096
#define D_ 128
#define K_ 8

// ---------------------------------------------------------------------------
// Prep: pack points as float4(x,y,z,|p|^2) with |p|^2 = (z*z+y*y)+x*x
// (descending plain — the verified oracle rounding), no contraction.
// ---------------------------------------------------------------------------
__global__ __launch_bounds__(256) void prep_kernel(
    const float* __restrict__ pts, float4* __restrict__ pts4)
{
#pragma clang fp contract(off)
    const int i = blockIdx.x * 256 + threadIdx.x;
    if (i < B_ * N_) {
        const float x = pts[i * 3 + 0];
        const float y = pts[i * 3 + 1];
        const float z = pts[i * 3 + 2];
        float4 v;
        v.x = x; v.y = y; v.z = z;
        v.w = (z * z + y * y) + x * x;          // DESCENDING, no fma
        pts4[i] = v;
    }
}

// ---------------------------------------------------------------------------
// knn: verified oracle semantics (FROZEN):
//   sg2 = (gz*gz+gy*gy)+gx*gx   descending plain
//   dot = fma(gz,pz, fma(gy,py, gx*px))  ascending FMA chain
//   d2  = fma(dot,-2, sg2+sp2)  == (sg2+sp2) - 2*dot bitwise (2*dot exact)
//   dist= sqrtf(fmaxf(d2,0)); rank by dist, strict < (lowest-index ties)
// Structure: block = 512 thr = 8 waves; block owns 64 queries (lane l of
// every wave -> query qbase+l); wave w scans point EIGHTH [w*512,(w+1)*512)
// ascending. Points read as wave-uniform float4 (scalar-cache broadcast, no
// LDS staging). grid = 1024 blocks -> 4 blocks/CU x 8 waves = 100% occupancy.
// 8 partial lists merged via LDS (lane stride 73 = odd -> conflict-free),
// h ascending = ascending index blocks -> stable lowest-index ties.
// ---------------------------------------------------------------------------
__global__ __launch_bounds__(512) void knn_kernel(
    const float* __restrict__ grid_c, const float4* __restrict__ pts4,
    int* __restrict__ out_idx, float* __restrict__ out_w)
{
#pragma clang fp contract(off)
    __shared__ float sd[64][73];   // [q_local][wave*9 + u], stride 73 (odd)
    __shared__ int   si[64][73];

    const int tid   = threadIdx.x;
    const int wv    = tid >> 6;                 // 0..7
    const int lane  = tid & 63;
    const int qbase = blockIdx.x * 64;          // 32768 % 64 == 0 -> uniform b
    const int b     = qbase >> 15;
    const int q     = qbase + lane;

    const float gx = grid_c[q * 3 + 0];
    const float gy = grid_c[q * 3 + 1];
    const float gz = grid_c[q * 3 + 2];
    const float sg2 = (gz * gz + gy * gy) + gx * gx;   // DESCENDING, no fma

    float bd[8];
    int   bi[8];
#pragma unroll
    for (int u = 0; u < 8; ++u) { bd[u] = 3.4e38f; bi[u] = 0; }

    const int toff = wv * (N_ / 8);
    const float4* __restrict__ pb4 = pts4 + (size_t)b * N_ + toff;

    for (int t = 0; t < N_ / 8; t += 2) {
        const float4 p0 = pb4[t];               // wave-uniform -> scalar load
        const float4 p1 = pb4[t + 1];
        const float dot0 = fmaf(gz, p0.z, fmaf(gy, p0.y, gx * p0.x));
        const float dot1 = fmaf(gz, p1.z, fmaf(gy, p1.y, gx * p1.x));
        const float d20  = fmaf(dot0, -2.0f, sg2 + p0.w);  // == (A+B)-2*dot
        const float d21  = fmaf(dot1, -2.0f, sg2 + p1.w);
        const float dist0 = sqrtf(fmaxf(d20, 0.0f));
        const float dist1 = sqrtf(fmaxf(d21, 0.0f));
        if (dist0 < bd[7]) {                    // strict <: stable ties
            bd[7] = dist0; bi[7] = toff + t;
#pragma unroll
            for (int u = 6; u >= 0; --u) {
                if (bd[u + 1] < bd[u]) {
                    float tf = bd[u]; bd[u] = bd[u + 1]; bd[u + 1] = tf;
                    int   ti = bi[u]; bi[u] = bi[u + 1]; bi[u + 1] = ti;
                }
            }
        }
        if (dist1 < bd[7]) {
            bd[7] = dist1; bi[7] = toff + t + 1;
#pragma unroll
            for (int u = 6; u >= 0; --u) {
                if (bd[u + 1] < bd[u]) {
                    float tf = bd[u]; bd[u] = bd[u + 1]; bd[u + 1] = tf;
                    int   ti = bi[u]; bi[u] = bi[u + 1]; bi[u + 1] = ti;
                }
            }
        }
    }

#pragma unroll
    for (int u = 0; u < 8; ++u) {
        sd[lane][wv * 9 + u] = bd[u];
        si[lane][wv * 9 + u] = bi[u];
    }
    __syncthreads();

    if (tid < 64) {
        float ed[8];
        int   ei[8];
#pragma unroll
        for (int u = 0; u < 8; ++u) { ed[u] = 3.4e38f; ei[u] = 0; }
        // h ascending = ascending index blocks -> stable lowest-index ties
        for (int h = 0; h < 8; ++h) {
#pragma unroll
            for (int u2 = 0; u2 < 8; ++u2) {
                float v  = sd[tid][h * 9 + u2];
                int   vi = si[tid][h * 9 + u2];
                if (v < ed[7]) {
                    ed[7] = v; ei[7] = vi;
#pragma unroll
                    for (int u = 6; u >= 0; --u) {
                        if (ed[u + 1] < ed[u]) {
                            float tf = ed[u]; ed[u] = ed[u + 1]; ed[u + 1] = tf;
                            int   ti = ei[u]; ei[u] = ei[u + 1]; ei[u + 1] = ti;
                        }
                    }
                }
            }
        }
        // inverse-distance weights (verified rounding: f32, sequential sum)
        float wk8[8];
#pragma unroll
        for (int u = 0; u < 8; ++u)
            wk8[u] = 1.0f / (ed[u] + 1e-6f);
        float wsum = wk8[0];
#pragma unroll
        for (int u = 1; u < 8; ++u) wsum = wsum + wk8[u];
        const float winv = 1.0f / wsum;
        const int qq = qbase + tid;
#pragma unroll
        for (int u = 0; u < 8; ++u) {
            out_idx[qq * 8 + u] = ei[u];
            out_w[qq * 8 + u]   = wk8[u] * winv;
        }
    }
}

// ---------------------------------------------------------------------------
// gno: per-neighbor MLP + weighted reduce + LayerNorm (continuous path).
// Phase B uses float4 LDS reads (ds_read_b128); W1 rows in registers.
// ---------------------------------------------------------------------------
__global__ __launch_bounds__(256) void gno_kernel(
    const float* __restrict__ grid_c, const float* __restrict__ pts,
    const float* __restrict__ feats,
    const float* __restrict__ W1, const float* __restrict__ b1,
    const float* __restrict__ W2, const float* __restrict__ b2,
    const float* __restrict__ gmm, const float* __restrict__ bta,
    const int* __restrict__ kidx, const float* __restrict__ kw,
    float* __restrict__ out)
{
    __shared__ float sh[8][8][D_];      // [q][k][j]  32 KB
    __shared__ float srel[8][8][4];
    __shared__ float swt[8][8];
    __shared__ int   sid[8][8];

    const int tid = threadIdx.x;
    const int qb8 = blockIdx.x * 8;

    if (tid < 64) {
        const int qq = tid >> 3, k = tid & 7;
        const int gq = qb8 + qq;
        const int id = kidx[gq * 8 + k];
        sid[qq][k] = id;
        swt[qq][k] = kw[gq * 8 + k];
        const int bb = gq >> 15;
        const float* pp = pts + ((size_t)bb * N_ + id) * 3;
        srel[qq][k][0] = grid_c[gq * 3 + 0] - pp[0];
        srel[qq][k][1] = grid_c[gq * 3 + 1] - pp[1];
        srel[qq][k][2] = grid_c[gq * 3 + 2] - pp[2];
    }

    const int qs = tid >> 5;
    const int dg = tid & 31;

    const float4 w1r0 = *(const float4*)(W1 + dg * 4);
    const float4 w1r1 = *(const float4*)(W1 + D_ + dg * 4);
    const float4 w1r2 = *(const float4*)(W1 + 2 * D_ + dg * 4);
    const float4 w1bb = *(const float4*)(b1 + dg * 4);
    __syncthreads();

    // ---- Phase A: h into LDS --------------------------------------------
#pragma unroll
    for (int k = 0; k < 8; ++k) {
        const float rx = srel[qs][k][0];
        const float ry = srel[qs][k][1];
        const float rz = srel[qs][k][2];
        float hr[4];
        {
            float u0 = rx * w1r0.x + ry * w1r1.x + rz * w1r2.x + w1bb.x;
            float u1 = rx * w1r0.y + ry * w1r1.y + rz * w1r2.y + w1bb.y;
            float u2 = rx * w1r0.z + ry * w1r1.z + rz * w1r2.z + w1bb.z;
            float u3 = rx * w1r0.w + ry * w1r1.w + rz * w1r2.w + w1bb.w;
            hr[0] = 0.5f * u0 * (1.0f + erff(u0 * 0.70710678118654752f));
            hr[1] = 0.5f * u1 * (1.0f + erff(u1 * 0.70710678118654752f));
            hr[2] = 0.5f * u2 * (1.0f + erff(u2 * 0.70710678118654752f));
            hr[3] = 0.5f * u3 * (1.0f + erff(u3 * 0.70710678118654752f));
        }
        *(float4*)&sh[qs][k][dg * 4] = *(float4*)hr;
    }
    __syncthreads();

    // ---- Phase B: kappa = h @ W2, combine -------------------------------
    float acc[8][4];
#pragma unroll
    for (int k = 0; k < 8; ++k)
#pragma unroll
        for (int c = 0; c < 4; ++c) acc[k][c] = 0.0f;

    const float* w2p = W2 + dg * 4;
    for (int j0 = 0; j0 < D_; j0 += 4) {
        float4 hv[8];
#pragma unroll
        for (int k = 0; k < 8; ++k)
            hv[k] = *(const float4*)&sh[qs][k][j0];
        const float4 wa = *(const float4*)(w2p + (size_t)j0 * D_);
        const float4 wb = *(const float4*)(w2p + (size_t)(j0 + 1) * D_);
        const float4 wc = *(const float4*)(w2p + (size_t)(j0 + 2) * D_);
        const float4 wd = *(const float4*)(w2p + (size_t)(j0 + 3) * D_);
#pragma unroll
        for (int k = 0; k < 8; ++k) {
            acc[k][0] += hv[k].x * wa.x; acc[k][1] += hv[k].x * wa.y;
            acc[k][2] += hv[k].x * wa.z; acc[k][3] += hv[k].x * wa.w;
            acc[k][0] += hv[k].y * wb.x; acc[k][1] += hv[k].y * wb.y;
            acc[k][2] += hv[k].y * wb.z; acc[k][3] += hv[k].y * wb.w;
            acc[k][0] += hv[k].z * wc.x; acc[k][1] += hv[k].z * wc.y;
            acc[k][2] += hv[k].z * wc.z; acc[k][3] += hv[k].z * wc.w;
            acc[k][0] += hv[k].w * wd.x; acc[k][1] += hv[k].w * wd.y;
            acc[k][2] += hv[k].w * wd.z; acc[k][3] += hv[k].w * wd.w;
        }
    }

    const int gq = qb8 + qs;
    const int bb = gq >> 15;
    const float4 b2v = *(const float4*)(b2 + dg * 4);

    float o0 = 0.0f, o1 = 0.0f, o2 = 0.0f, o3 = 0.0f;
#pragma unroll
    for (int k = 0; k < 8; ++k) {
        const float4 f =
            *(const float4*)(feats + ((size_t)bb * N_ + sid[qs][k]) * D_ + dg * 4);
        const float wk = swt[qs][k];
        o0 += wk * f.x * (acc[k][0] + b2v.x);
        o1 += wk * f.y * (acc[k][1] + b2v.y);
        o2 += wk * f.z * (acc[k][2] + b2v.z);
        o3 += wk * f.w * (acc[k][3] + b2v.w);
    }

    // ---- LayerNorm over D=128 (32 lanes x 4 vals) -----------------------
    float s = o0 + o1 + o2 + o3;
#pragma unroll
    for (int off = 16; off > 0; off >>= 1) s += __shfl_xor(s, off, 32);
    const float mu = s * (1.0f / 128.0f);
    const float v0 = o0 - mu, v1 = o1 - mu, v2 = o2 - mu, v3 = o3 - mu;
    float vs = v0 * v0 + v1 * v1 + v2 * v2 + v3 * v3;
#pragma unroll
    for (int off = 16; off > 0; off >>= 1) vs += __shfl_xor(vs, off, 32);
    const float inv = 1.0f / sqrtf(vs * (1.0f / 128.0f) + 1e-5f);

    const float4 gv = *(const float4*)(gmm + dg * 4);
    const float4 bv = *(const float4*)(bta + dg * 4);
    float4 ov;
    ov.x = v0 * inv * gv.x + bv.x;
    ov.y = v1 * inv * gv.y + bv.y;
    ov.z = v2 * inv * gv.z + bv.z;
    ov.w = v3 * inv * gv.w + bv.w;
    *(float4*)(out + (size_t)gq * D_ + dg * 4) = ov;
}

// ---------------------------------------------------------------------------
extern "C" void kernel_launch(void* const* d_in, const int* in_sizes, int n_in,
                              void* d_out, int out_size, void* d_ws, size_t ws_size,
                              hipStream_t stream)
{
    (void)in_sizes; (void)n_in; (void)out_size; (void)ws_size;
    const float* grid_c = (const float*)d_in[0];
    const float* pts    = (const float*)d_in[1];
    const float* feats  = (const float*)d_in[2];
    const float* W1     = (const float*)d_in[3];
    const float* b1     = (const float*)d_in[4];
    const float* W2     = (const float*)d_in[5];
    const float* b2     = (const float*)d_in[6];
    const float* gmm    = (const float*)d_in[7];
    const float* bta    = (const float*)d_in[8];
    float* out = (float*)d_out;

    int*    kidx = (int*)d_ws;                                        // 2 MB
    float*  kw   = (float*)((char*)d_ws + (size_t)B_ * M_ * K_ * 4);  // 2 MB
    float4* pts4 = (float4*)((char*)d_ws + (size_t)B_ * M_ * K_ * 8); // 128 KB

    prep_kernel<<<(B_ * N_ + 255) / 256, 256, 0, stream>>>(pts, pts4);
    knn_kernel<<<(B_ * M_) / 64, 512, 0, stream>>>(grid_c, pts4, kidx, kw);
    gno_kernel<<<(B_ * M_) / 8, 256, 0, stream>>>(grid_c, pts, feats, W1, b1,
                                                  W2, b2, gmm, bta, kidx, kw, out);
}